// Round 1
// baseline (496.494 us; speedup 1.0000x reference)
//
#include <hip/hip_runtime.h>
#include <cstdint>
#include <cstddef>

typedef unsigned short u16;
typedef float f32x4 __attribute__((ext_vector_type(4)));
typedef short s16x8 __attribute__((ext_vector_type(8)));

#define DI __device__ __forceinline__

static constexpr int S_  = 2048;
static constexpr int D_  = 2048;
static constexpr int H_  = 16;
static constexpr int HD_ = 128;
static constexpr int HHD = 2048;   // H*HD
static constexpr int CQP = 128;    // CQ=96 padded to 128
static constexpr int CKV_ = 512;
static constexpr int G_  = 8;      // heads per attention group (P buffer = G*S*S bf16)

DI u16 f2bf(float f) {
  unsigned u = __float_as_uint(f);
  u += 0x7fffu + ((u >> 16) & 1u);   // round-to-nearest-even
  return (u16)(u >> 16);
}
DI float bf2f(u16 h) { return __uint_as_float(((unsigned)h) << 16); }

DI void store_c(float* C, long long i, float v) { C[i] = v; }
DI void store_c(u16* C, long long i, float v) { C[i] = f2bf(v); }

// async 16B/lane global->LDS; LDS dest is wave-uniform base + lane*16
#define GLD16(g, l)                                                        \
  __builtin_amdgcn_global_load_lds(                                        \
      (__attribute__((address_space(1))) void*)(void*)(const void*)(g),    \
      (__attribute__((address_space(3))) void*)(l), 16, 0, 0)

// ---------------------------------------------------------------------------
// C[m][n] = sum_k A[m][k] * B[n][k]  (+bias_col[n]) (+bias_row[m])
// A: M x K row-major (lda), B: N x K row-major (ldb), C: M x N (ldc)
// Tile 128x128, BK=32, 256 threads (4 waves, each 64x64 = 4x4 MFMA tiles).
// blockIdx.z batches with element strides sA/sB/sC. M,N mult of 128, K mult 32.
// ---------------------------------------------------------------------------
template <typename OutT, int BCOL, int BROW>
__global__ __launch_bounds__(256) void gemm_bt(
    const u16* __restrict__ A, const u16* __restrict__ B, OutT* __restrict__ C,
    const float* __restrict__ bias_col, const float* __restrict__ bias_row,
    int K, int lda, int ldb, int ldc,
    long long sA, long long sB, long long sC) {
  __shared__ __align__(16) u16 As[128 * 32];
  __shared__ __align__(16) u16 Bs[128 * 32];
  const int tid  = threadIdx.x;
  const int w    = tid >> 6;
  const int lane = tid & 63;
  const int lr   = lane & 15;
  const int lq   = lane >> 4;
  const long long m0 = (long long)blockIdx.y * 128;
  const long long n0 = (long long)blockIdx.x * 128;
  A += (long long)blockIdx.z * sA;
  B += (long long)blockIdx.z * sB;
  C += (long long)blockIdx.z * sC;
  const int wr = (w >> 1) * 64;
  const int wc = (w & 1) * 64;

  f32x4 acc[4][4];
#pragma unroll
  for (int i = 0; i < 4; ++i)
#pragma unroll
    for (int j = 0; j < 4; ++j)
#pragma unroll
      for (int r = 0; r < 4; ++r) acc[i][j][r] = 0.f;

  // staging: chunk c covers A/B row c>>2, k-offset (c&3)*8 (16B)
  const int c0 = (w * 2 + 0) * 64 + lane;
  const int c1 = (w * 2 + 1) * 64 + lane;
  const u16* a0 = A + (m0 + (c0 >> 2)) * lda + (c0 & 3) * 8;
  const u16* a1 = A + (m0 + (c1 >> 2)) * lda + (c1 & 3) * 8;
  const u16* b0 = B + (n0 + (c0 >> 2)) * ldb + (c0 & 3) * 8;
  const u16* b1 = B + (n0 + (c1 >> 2)) * ldb + (c1 & 3) * 8;
  u16* as0 = &As[(w * 2 + 0) * 512];
  u16* as1 = &As[(w * 2 + 1) * 512];
  u16* bs0 = &Bs[(w * 2 + 0) * 512];
  u16* bs1 = &Bs[(w * 2 + 1) * 512];

  for (int kt = 0; kt < K; kt += 32) {
    __syncthreads();
    GLD16(a0 + kt, as0);
    GLD16(a1 + kt, as1);
    GLD16(b0 + kt, bs0);
    GLD16(b1 + kt, bs1);
    __syncthreads();

    s16x8 af[4], bfr[4];
#pragma unroll
    for (int tm = 0; tm < 4; ++tm)
      af[tm] = *(const s16x8*)&As[(wr + tm * 16 + lr) * 32 + lq * 8];
#pragma unroll
    for (int tn = 0; tn < 4; ++tn)
      bfr[tn] = *(const s16x8*)&Bs[(wc + tn * 16 + lr) * 32 + lq * 8];
#pragma unroll
    for (int tm = 0; tm < 4; ++tm)
#pragma unroll
      for (int tn = 0; tn < 4; ++tn)
        acc[tm][tn] = __builtin_amdgcn_mfma_f32_16x16x32_bf16(af[tm], bfr[tn],
                                                              acc[tm][tn], 0, 0, 0);
  }

  // C/D layout: col = lane&15, row = (lane>>4)*4 + reg
#pragma unroll
  for (int tm = 0; tm < 4; ++tm)
#pragma unroll
    for (int tn = 0; tn < 4; ++tn) {
      const long long col = n0 + wc + tn * 16 + lr;
      float bc = BCOL ? bias_col[col] : 0.f;
#pragma unroll
      for (int r = 0; r < 4; ++r) {
        const long long row = m0 + wr + tm * 16 + lq * 4 + r;
        float v = acc[tm][tn][r] + bc;
        if (BROW) v += bias_row[row];
        store_c(C, row * (long long)ldc + col, v);
      }
    }
}

// ---------------------------------------------------------------------------
__global__ __launch_bounds__(256) void cast_f32_bf16(const float* __restrict__ s,
                                                     u16* __restrict__ d, int n4) {
  int i = blockIdx.x * 256 + threadIdx.x;
  if (i >= n4) return;
  float4 f = ((const float4*)s)[i];
  unsigned lo = (unsigned)f2bf(f.x) | ((unsigned)f2bf(f.y) << 16);
  unsigned hi = (unsigned)f2bf(f.z) | ((unsigned)f2bf(f.w) << 16);
  ((uint2*)d)[i] = make_uint2(lo, hi);
}

// dst is rows_d x cd (bf16), src rs x cs (f32); zero-pad outside
__global__ __launch_bounds__(256) void pad_cast2d(const float* __restrict__ s,
                                                  u16* __restrict__ d, int rs, int cs,
                                                  int cd, int nd) {
  int i = blockIdx.x * 256 + threadIdx.x;
  if (i >= nd) return;
  int r = i / cd, c = i % cd;
  float v = (r < rs && c < cs) ? s[r * cs + c] : 0.f;
  d[i] = f2bf(v);
}

__global__ void pad_bias(const float* __restrict__ s, float* __restrict__ d, int ns,
                         int nd) {
  int i = threadIdx.x;
  if (i < nd) d[i] = (i < ns) ? s[i] : 0.f;
}

// in-place RoPE on (S, H, HD) bf16, thread handles the (d, d+64) pair
__global__ __launch_bounds__(256) void rope_inplace(u16* __restrict__ X,
                                                    const float* __restrict__ cs,
                                                    const float* __restrict__ sn,
                                                    float scale) {
  int id = blockIdx.x * 256 + threadIdx.x;  // S*H*64 total
  int d = id & 63;
  int h = (id >> 6) & 15;
  int s = id >> 10;
  long long b = (long long)s * HHD + h * HD_ + d;
  float x1 = bf2f(X[b]), x2 = bf2f(X[b + 64]);
  int cb = s * HD_ + d;
  float o1 = (x1 * cs[cb] - x2 * sn[cb]) * scale;
  float o2 = (x2 * cs[cb + 64] + x1 * sn[cb + 64]) * scale;
  X[b] = f2bf(o1);
  X[b + 64] = f2bf(o2);
}

// row softmax in place on bf16 rows of length 2048; grid (rows, z)
__global__ __launch_bounds__(256) void softmax_rows(u16* __restrict__ P,
                                                    long long strideZ) {
  const int t = threadIdx.x;
  u16* row = P + (long long)blockIdx.y * strideZ + (long long)blockIdx.x * 2048;
  uint4 pk = *(const uint4*)(row + t * 8);
  unsigned uw[4] = {pk.x, pk.y, pk.z, pk.w};
  float v[8];
#pragma unroll
  for (int i = 0; i < 4; ++i) {
    v[2 * i]     = bf2f((u16)(uw[i] & 0xffffu));
    v[2 * i + 1] = bf2f((u16)(uw[i] >> 16));
  }
  float mx = -3.0e38f;
#pragma unroll
  for (int i = 0; i < 8; ++i) mx = fmaxf(mx, v[i]);
  for (int off = 32; off; off >>= 1) mx = fmaxf(mx, __shfl_xor(mx, off));
  __shared__ float rmax[4], rsum[4];
  if ((t & 63) == 0) rmax[t >> 6] = mx;
  __syncthreads();
  mx = fmaxf(fmaxf(rmax[0], rmax[1]), fmaxf(rmax[2], rmax[3]));
  float sum = 0.f;
#pragma unroll
  for (int i = 0; i < 8; ++i) {
    v[i] = __expf(v[i] - mx);
    sum += v[i];
  }
  for (int off = 32; off; off >>= 1) sum += __shfl_xor(sum, off);
  if ((t & 63) == 0) rsum[t >> 6] = sum;
  __syncthreads();
  sum = rsum[0] + rsum[1] + rsum[2] + rsum[3];
  float inv = 1.f / sum;
#pragma unroll
  for (int i = 0; i < 4; ++i)
    uw[i] = (unsigned)f2bf(v[2 * i] * inv) | ((unsigned)f2bf(v[2 * i + 1] * inv) << 16);
  *(uint4*)(row + t * 8) = make_uint4(uw[0], uw[1], uw[2], uw[3]);
}

// ---------------------------------------------------------------------------
extern "C" void kernel_launch(void* const* d_in, const int* in_sizes, int n_in,
                              void* d_out, int out_size, void* d_ws, size_t ws_size,
                              hipStream_t stream) {
  (void)in_sizes; (void)n_in; (void)out_size; (void)ws_size;
  const float* x        = (const float*)d_in[0];
  const float* rc       = (const float*)d_in[1];
  const float* rs       = (const float*)d_in[2];
  const float* wq_down  = (const float*)d_in[3];
  const float* bq_down  = (const float*)d_in[4];
  const float* wq_up    = (const float*)d_in[5];
  const float* bq_up    = (const float*)d_in[6];
  const float* wkv_down = (const float*)d_in[7];
  const float* bkv_down = (const float*)d_in[8];
  const float* wk_up    = (const float*)d_in[9];
  const float* bk_up    = (const float*)d_in[10];
  const float* wv_up    = (const float*)d_in[11];
  const float* bv_up    = (const float*)d_in[12];
  const float* wo       = (const float*)d_in[13];
  const float* bo       = (const float*)d_in[14];
  float* out = (float*)d_out;

  char* ws = (char*)d_ws;
  size_t off = 0;
  auto alloc = [&](size_t bytes) -> void* {
    off = (off + 255) & ~(size_t)255;
    void* p = ws + off;
    off += bytes;
    return p;
  };

  u16* xb    = (u16*)alloc((size_t)S_ * D_ * 2);
  u16* wqd   = (u16*)alloc((size_t)CQP * D_ * 2);
  u16* wqu   = (u16*)alloc((size_t)HHD * CQP * 2);
  float* bqd = (float*)alloc(CQP * 4);
  u16* wkvd  = (u16*)alloc((size_t)CKV_ * D_ * 2);
  u16* wku   = (u16*)alloc((size_t)HHD * CKV_ * 2);
  u16* wvu   = (u16*)alloc((size_t)HHD * CKV_ * 2);
  u16* wob   = (u16*)alloc((size_t)D_ * HHD * 2);
  u16* cq    = (u16*)alloc((size_t)S_ * CQP * 2);
  u16* ckv   = (u16*)alloc((size_t)S_ * CKV_ * 2);
  u16* qb    = (u16*)alloc((size_t)S_ * HHD * 2);
  u16* kb    = (u16*)alloc((size_t)S_ * HHD * 2);
  u16* vT    = (u16*)alloc((size_t)HHD * S_ * 2);   // [hd][S]
  u16* attnb = (u16*)alloc((size_t)S_ * HHD * 2);
  u16* P     = (u16*)alloc((size_t)G_ * S_ * S_ * 2);

  // ---- casts / padding ----
  cast_f32_bf16<<<(S_ * D_ / 4 + 255) / 256, 256, 0, stream>>>(x, xb, S_ * D_ / 4);
  pad_cast2d<<<(CQP * D_ + 255) / 256, 256, 0, stream>>>(wq_down, wqd, 96, D_, D_, CQP * D_);
  pad_cast2d<<<(HHD * CQP + 255) / 256, 256, 0, stream>>>(wq_up, wqu, HHD, 96, CQP, HHD * CQP);
  pad_bias<<<1, 128, 0, stream>>>(bq_down, bqd, 96, CQP);
  cast_f32_bf16<<<(CKV_ * D_ / 4 + 255) / 256, 256, 0, stream>>>(wkv_down, wkvd, CKV_ * D_ / 4);
  cast_f32_bf16<<<(HHD * CKV_ / 4 + 255) / 256, 256, 0, stream>>>(wk_up, wku, HHD * CKV_ / 4);
  cast_f32_bf16<<<(HHD * CKV_ / 4 + 255) / 256, 256, 0, stream>>>(wv_up, wvu, HHD * CKV_ / 4);
  cast_f32_bf16<<<(D_ * HHD / 4 + 255) / 256, 256, 0, stream>>>(wo, wob, D_ * HHD / 4);

  // ---- projections ----
  // c_q (S x CQP) = x @ wq_down_pad^T + bq_down_pad
  gemm_bt<u16, 1, 0><<<dim3(1, 16, 1), 256, 0, stream>>>(
      xb, wqd, cq, bqd, nullptr, D_, D_, D_, CQP, 0, 0, 0);
  // c_kv (S x CKV) = x @ wkv_down^T + bkv_down
  gemm_bt<u16, 1, 0><<<dim3(CKV_ / 128, 16, 1), 256, 0, stream>>>(
      xb, wkvd, ckv, bkv_down, nullptr, D_, D_, D_, CKV_, 0, 0, 0);
  // q (S x HHD) = c_q @ wq_up_pad^T + bq_up
  gemm_bt<u16, 1, 0><<<dim3(16, 16, 1), 256, 0, stream>>>(
      cq, wqu, qb, bq_up, nullptr, CQP, CQP, CQP, HHD, 0, 0, 0);
  // k (S x HHD) = c_kv @ wk_up^T + bk_up
  gemm_bt<u16, 1, 0><<<dim3(16, 16, 1), 256, 0, stream>>>(
      ckv, wku, kb, bk_up, nullptr, CKV_, CKV_, CKV_, HHD, 0, 0, 0);
  // vT (HHD x S) = wv_up @ c_kv^T  (+ bv_up per ROW) == v transposed
  gemm_bt<u16, 0, 1><<<dim3(16, 16, 1), 256, 0, stream>>>(
      wvu, ckv, vT, nullptr, bv_up, CKV_, CKV_, CKV_, S_, 0, 0, 0);

  // ---- RoPE (q also scaled by 1/sqrt(HD)) ----
  rope_inplace<<<(S_ * H_ * 64) / 256, 256, 0, stream>>>(qb, rc, rs, 0.08838834764831845f);
  rope_inplace<<<(S_ * H_ * 64) / 256, 256, 0, stream>>>(kb, rc, rs, 1.0f);

  // ---- attention, G_ heads per group ----
  const long long SS = (long long)S_ * S_;
  for (int g = 0; g < H_ / G_; ++g) {
    // logits[h] (S x S) = q_h @ k_h^T   (q pre-scaled)
    gemm_bt<u16, 0, 0><<<dim3(16, 16, G_), 256, 0, stream>>>(
        qb + (size_t)g * G_ * HD_, kb + (size_t)g * G_ * HD_, P, nullptr, nullptr,
        HD_, HHD, HHD, S_, HD_, HD_, SS);
    softmax_rows<<<dim3(S_, G_, 1), 256, 0, stream>>>(P, SS);
    // attn_h (S x HD) = P_h @ vT_h^T   -> attnb[:, h*128:...]
    gemm_bt<u16, 0, 0><<<dim3(1, 16, G_), 256, 0, stream>>>(
        P, vT + (size_t)g * G_ * HD_ * S_, attnb + (size_t)g * G_ * HD_, nullptr,
        nullptr, S_, S_, S_, HHD, SS, (long long)HD_ * S_, HD_);
  }

  // ---- output projection (fp32 out) ----
  gemm_bt<float, 1, 0><<<dim3(16, 16, 1), 256, 0, stream>>>(
      attnb, wob, out, bo, nullptr, HHD, HHD, HHD, D_, 0, 0, 0);
}

// Round 2
// 433.802 us; speedup vs baseline: 1.1445x; 1.1445x over previous
//
#include <hip/hip_runtime.h>
#include <cstdint>
#include <cstddef>

typedef unsigned short u16;
typedef float f32x4 __attribute__((ext_vector_type(4)));
typedef short s16x8 __attribute__((ext_vector_type(8)));

#define DI __device__ __forceinline__

static constexpr int S_  = 2048;
static constexpr int D_  = 2048;
static constexpr int H_  = 16;
static constexpr int HD_ = 128;
static constexpr int HHD = 2048;   // H*HD
static constexpr int CQP = 128;    // CQ=96 padded to 128
static constexpr int CKV_ = 512;

DI u16 f2bf(float f) {
  unsigned u = __float_as_uint(f);
  u += 0x7fffu + ((u >> 16) & 1u);   // round-to-nearest-even
  return (u16)(u >> 16);
}
DI float bf2f(u16 h) { return __uint_as_float(((unsigned)h) << 16); }

DI void store_c(float* C, long long i, float v) { C[i] = v; }
DI void store_c(u16* C, long long i, float v) { C[i] = f2bf(v); }

// async 16B/lane global->LDS; LDS dest is wave-uniform base + lane*16
#define GLD16(g, l)                                                        \
  __builtin_amdgcn_global_load_lds(                                        \
      (__attribute__((address_space(1))) void*)(void*)(const void*)(g),    \
      (__attribute__((address_space(3))) void*)(l), 16, 0, 0)

// ---------------------------------------------------------------------------
// C[m][n] = sum_k A[m][k] * B[n][k]  (+bias_col[n]) (+bias_row[m])
// ---------------------------------------------------------------------------
template <typename OutT, int BCOL, int BROW>
__global__ __launch_bounds__(256) void gemm_bt(
    const u16* __restrict__ A, const u16* __restrict__ B, OutT* __restrict__ C,
    const float* __restrict__ bias_col, const float* __restrict__ bias_row,
    int K, int lda, int ldb, int ldc,
    long long sA, long long sB, long long sC) {
  __shared__ __align__(16) u16 As[128 * 32];
  __shared__ __align__(16) u16 Bs[128 * 32];
  const int tid  = threadIdx.x;
  const int w    = tid >> 6;
  const int lane = tid & 63;
  const int lr   = lane & 15;
  const int lq   = lane >> 4;
  const long long m0 = (long long)blockIdx.y * 128;
  const long long n0 = (long long)blockIdx.x * 128;
  A += (long long)blockIdx.z * sA;
  B += (long long)blockIdx.z * sB;
  C += (long long)blockIdx.z * sC;
  const int wr = (w >> 1) * 64;
  const int wc = (w & 1) * 64;

  f32x4 acc[4][4];
#pragma unroll
  for (int i = 0; i < 4; ++i)
#pragma unroll
    for (int j = 0; j < 4; ++j)
#pragma unroll
      for (int r = 0; r < 4; ++r) acc[i][j][r] = 0.f;

  const int c0 = (w * 2 + 0) * 64 + lane;
  const int c1 = (w * 2 + 1) * 64 + lane;
  const u16* a0 = A + (m0 + (c0 >> 2)) * lda + (c0 & 3) * 8;
  const u16* a1 = A + (m0 + (c1 >> 2)) * lda + (c1 & 3) * 8;
  const u16* b0 = B + (n0 + (c0 >> 2)) * ldb + (c0 & 3) * 8;
  const u16* b1 = B + (n0 + (c1 >> 2)) * ldb + (c1 & 3) * 8;
  u16* as0 = &As[(w * 2 + 0) * 512];
  u16* as1 = &As[(w * 2 + 1) * 512];
  u16* bs0 = &Bs[(w * 2 + 0) * 512];
  u16* bs1 = &Bs[(w * 2 + 1) * 512];

  for (int kt = 0; kt < K; kt += 32) {
    __syncthreads();
    GLD16(a0 + kt, as0);
    GLD16(a1 + kt, as1);
    GLD16(b0 + kt, bs0);
    GLD16(b1 + kt, bs1);
    __syncthreads();

    s16x8 af[4], bfr[4];
#pragma unroll
    for (int tm = 0; tm < 4; ++tm)
      af[tm] = *(const s16x8*)&As[(wr + tm * 16 + lr) * 32 + lq * 8];
#pragma unroll
    for (int tn = 0; tn < 4; ++tn)
      bfr[tn] = *(const s16x8*)&Bs[(wc + tn * 16 + lr) * 32 + lq * 8];
#pragma unroll
    for (int tm = 0; tm < 4; ++tm)
#pragma unroll
      for (int tn = 0; tn < 4; ++tn)
        acc[tm][tn] = __builtin_amdgcn_mfma_f32_16x16x32_bf16(af[tm], bfr[tn],
                                                              acc[tm][tn], 0, 0, 0);
  }

#pragma unroll
  for (int tm = 0; tm < 4; ++tm)
#pragma unroll
    for (int tn = 0; tn < 4; ++tn) {
      const long long col = n0 + wc + tn * 16 + lr;
      float bc = BCOL ? bias_col[col] : 0.f;
#pragma unroll
      for (int r = 0; r < 4; ++r) {
        const long long row = m0 + wr + tm * 16 + lq * 4 + r;
        float v = acc[tm][tn][r] + bc;
        if (BROW) v += bias_row[row];
        store_c(C, row * (long long)ldc + col, v);
      }
    }
}

// ---------------------------------------------------------------------------
// Fused flash attention: one block per (head, q-tile of 128).
// 4 waves; wave w owns q-rows [w*32, w*32+32) via two 16x16x32 m-frags.
// K_j tile (128 keys x 128 d) and V_j^T tile (128 d x 128 keys, from vT)
// staged via global_load_lds; staging for j+1 overlaps compute of j.
// ---------------------------------------------------------------------------
__global__ __launch_bounds__(256, 1) void flash_attn(
    const u16* __restrict__ Q, const u16* __restrict__ Kg,
    const u16* __restrict__ Vt, u16* __restrict__ Og) {
  __shared__ __align__(16) u16 Ks[128 * 128];   // [key][d]
  __shared__ __align__(16) u16 Vs[128 * 128];   // [d][key]
  __shared__ __align__(16) u16 Ps[128 * 136];   // [q][key], +8 pad
  const int h = blockIdx.x;
  const int t = blockIdx.y;
  const int tid = threadIdx.x;
  const int w = tid >> 6, lane = tid & 63, lr = lane & 15, lq = lane >> 4;
  const int qg = t * 128 + w * 32;
  const int tr = tid >> 4, tc = (tid & 15) * 8;

  // Q fragments in registers (A-layout): A[m=qg+mi*16+lr][k=kst*32+lq*8]
  s16x8 qf[2][4];
#pragma unroll
  for (int mi = 0; mi < 2; ++mi)
#pragma unroll
    for (int kst = 0; kst < 4; ++kst)
      qf[mi][kst] = *(const s16x8*)&Q[(size_t)(qg + mi * 16 + lr) * HHD +
                                      h * HD_ + kst * 32 + lq * 8];

  f32x4 oacc[2][8];
  float m[2][4], l[2][4];
#pragma unroll
  for (int mi = 0; mi < 2; ++mi) {
#pragma unroll
    for (int r = 0; r < 4; ++r) { m[mi][r] = -3.0e38f; l[mi][r] = 0.f; }
#pragma unroll
    for (int f = 0; f < 8; ++f)
#pragma unroll
      for (int r = 0; r < 4; ++r) oacc[mi][f][r] = 0.f;
  }

  auto stage_k = [&](int j) {
    const u16* s0 = Kg + (size_t)(j * 128 + tr) * HHD + h * HD_ + tc;
#pragma unroll
    for (int i = 0; i < 8; ++i)
      GLD16(s0 + (size_t)i * 16 * HHD, &Ks[i * 2048 + w * 512]);
  };
  auto stage_v = [&](int j) {
    const u16* s0 = Vt + (size_t)(h * 128 + tr) * S_ + j * 128 + tc;
#pragma unroll
    for (int i = 0; i < 8; ++i)
      GLD16(s0 + (size_t)i * 16 * S_, &Vs[i * 2048 + w * 512]);
  };

  stage_k(0);
  stage_v(0);
  __syncthreads();

  for (int j = 0; j < 16; ++j) {
    // ---- S = Q K^T ----
    f32x4 sacc[2][8];
#pragma unroll
    for (int mi = 0; mi < 2; ++mi)
#pragma unroll
      for (int f = 0; f < 8; ++f)
#pragma unroll
        for (int r = 0; r < 4; ++r) sacc[mi][f][r] = 0.f;
#pragma unroll
    for (int kst = 0; kst < 4; ++kst)
#pragma unroll
      for (int f = 0; f < 8; ++f) {
        s16x8 kf = *(const s16x8*)&Ks[(f * 16 + lr) * 128 + kst * 32 + lq * 8];
        sacc[0][f] = __builtin_amdgcn_mfma_f32_16x16x32_bf16(qf[0][kst], kf,
                                                             sacc[0][f], 0, 0, 0);
        sacc[1][f] = __builtin_amdgcn_mfma_f32_16x16x32_bf16(qf[1][kst], kf,
                                                             sacc[1][f], 0, 0, 0);
      }

    // ---- online softmax; C-layout row = lq*4 + r within each m-frag ----
#pragma unroll
    for (int mi = 0; mi < 2; ++mi)
#pragma unroll
      for (int r = 0; r < 4; ++r) {
        float mx = sacc[mi][0][r];
#pragma unroll
        for (int f = 1; f < 8; ++f) mx = fmaxf(mx, sacc[mi][f][r]);
        mx = fmaxf(mx, __shfl_xor(mx, 1));
        mx = fmaxf(mx, __shfl_xor(mx, 2));
        mx = fmaxf(mx, __shfl_xor(mx, 4));
        mx = fmaxf(mx, __shfl_xor(mx, 8));
        float mn = fmaxf(m[mi][r], mx);
        float al = __expf(m[mi][r] - mn);
        m[mi][r] = mn;
        float sum = 0.f;
#pragma unroll
        for (int f = 0; f < 8; ++f) {
          float p = __expf(sacc[mi][f][r] - mn);
          sacc[mi][f][r] = p;
          sum += p;
        }
        sum += __shfl_xor(sum, 1);
        sum += __shfl_xor(sum, 2);
        sum += __shfl_xor(sum, 4);
        sum += __shfl_xor(sum, 8);
        l[mi][r] = l[mi][r] * al + sum;
#pragma unroll
        for (int f = 0; f < 8; ++f) oacc[mi][f][r] *= al;
      }

    // ---- P -> LDS (bf16, [q][key], stride 136) ----
#pragma unroll
    for (int mi = 0; mi < 2; ++mi)
#pragma unroll
      for (int f = 0; f < 8; ++f)
#pragma unroll
        for (int r = 0; r < 4; ++r)
          Ps[(w * 32 + mi * 16 + lq * 4 + r) * 136 + f * 16 + lr] =
              f2bf(sacc[mi][f][r]);

    __syncthreads();               // all waves done reading Ks
    if (j < 15) stage_k(j + 1);    // K prefetch hidden under PV

    // ---- O += P V  (A = P rows [own q], B = Vs rows [d][key]) ----
#pragma unroll
    for (int kst = 0; kst < 4; ++kst) {
      s16x8 pa0 = *(const s16x8*)&Ps[(w * 32 + lr) * 136 + kst * 32 + lq * 8];
      s16x8 pa1 = *(const s16x8*)&Ps[(w * 32 + 16 + lr) * 136 + kst * 32 + lq * 8];
#pragma unroll
      for (int f = 0; f < 8; ++f) {
        s16x8 vf = *(const s16x8*)&Vs[(f * 16 + lr) * 128 + kst * 32 + lq * 8];
        oacc[0][f] = __builtin_amdgcn_mfma_f32_16x16x32_bf16(pa0, vf,
                                                             oacc[0][f], 0, 0, 0);
        oacc[1][f] = __builtin_amdgcn_mfma_f32_16x16x32_bf16(pa1, vf,
                                                             oacc[1][f], 0, 0, 0);
      }
    }
    __syncthreads();               // all waves done reading Vs; K_{j+1} drained
    if (j < 15) stage_v(j + 1);    // V prefetch hidden under next S-phase
  }

  // ---- epilogue: O / l -> attnb[q][h*128+d] ----
#pragma unroll
  for (int mi = 0; mi < 2; ++mi) {
    float inv[4];
#pragma unroll
    for (int r = 0; r < 4; ++r) inv[r] = 1.f / l[mi][r];
#pragma unroll
    for (int f = 0; f < 8; ++f)
#pragma unroll
      for (int r = 0; r < 4; ++r)
        Og[(size_t)(qg + mi * 16 + lq * 4 + r) * HHD + h * HD_ + f * 16 + lr] =
            f2bf(oacc[mi][f][r] * inv[r]);
  }
}

// ---------------------------------------------------------------------------
__global__ __launch_bounds__(256) void cast_f32_bf16(const float* __restrict__ s,
                                                     u16* __restrict__ d, int n4) {
  int i = blockIdx.x * 256 + threadIdx.x;
  if (i >= n4) return;
  float4 f = ((const float4*)s)[i];
  unsigned lo = (unsigned)f2bf(f.x) | ((unsigned)f2bf(f.y) << 16);
  unsigned hi = (unsigned)f2bf(f.z) | ((unsigned)f2bf(f.w) << 16);
  ((uint2*)d)[i] = make_uint2(lo, hi);
}

__global__ __launch_bounds__(256) void pad_cast2d(const float* __restrict__ s,
                                                  u16* __restrict__ d, int rs, int cs,
                                                  int cd, int nd) {
  int i = blockIdx.x * 256 + threadIdx.x;
  if (i >= nd) return;
  int r = i / cd, c = i % cd;
  float v = (r < rs && c < cs) ? s[r * cs + c] : 0.f;
  d[i] = f2bf(v);
}

__global__ void pad_bias(const float* __restrict__ s, float* __restrict__ d, int ns,
                         int nd) {
  int i = threadIdx.x;
  if (i < nd) d[i] = (i < ns) ? s[i] : 0.f;
}

__global__ __launch_bounds__(256) void rope_inplace(u16* __restrict__ X,
                                                    const float* __restrict__ cs,
                                                    const float* __restrict__ sn,
                                                    float scale) {
  int id = blockIdx.x * 256 + threadIdx.x;  // S*H*64 total
  int d = id & 63;
  int h = (id >> 6) & 15;
  int s = id >> 10;
  long long b = (long long)s * HHD + h * HD_ + d;
  float x1 = bf2f(X[b]), x2 = bf2f(X[b + 64]);
  int cb = s * HD_ + d;
  float o1 = (x1 * cs[cb] - x2 * sn[cb]) * scale;
  float o2 = (x2 * cs[cb + 64] + x1 * sn[cb + 64]) * scale;
  X[b] = f2bf(o1);
  X[b + 64] = f2bf(o2);
}

// ---------------------------------------------------------------------------
extern "C" void kernel_launch(void* const* d_in, const int* in_sizes, int n_in,
                              void* d_out, int out_size, void* d_ws, size_t ws_size,
                              hipStream_t stream) {
  (void)in_sizes; (void)n_in; (void)out_size; (void)ws_size;
  const float* x        = (const float*)d_in[0];
  const float* rc       = (const float*)d_in[1];
  const float* rs       = (const float*)d_in[2];
  const float* wq_down  = (const float*)d_in[3];
  const float* bq_down  = (const float*)d_in[4];
  const float* wq_up    = (const float*)d_in[5];
  const float* bq_up    = (const float*)d_in[6];
  const float* wkv_down = (const float*)d_in[7];
  const float* bkv_down = (const float*)d_in[8];
  const float* wk_up    = (const float*)d_in[9];
  const float* bk_up    = (const float*)d_in[10];
  const float* wv_up    = (const float*)d_in[11];
  const float* bv_up    = (const float*)d_in[12];
  const float* wo       = (const float*)d_in[13];
  const float* bo       = (const float*)d_in[14];
  float* out = (float*)d_out;

  char* ws = (char*)d_ws;
  size_t off = 0;
  auto alloc = [&](size_t bytes) -> void* {
    off = (off + 255) & ~(size_t)255;
    void* p = ws + off;
    off += bytes;
    return p;
  };

  u16* xb    = (u16*)alloc((size_t)S_ * D_ * 2);
  u16* wqd   = (u16*)alloc((size_t)CQP * D_ * 2);
  u16* wqu   = (u16*)alloc((size_t)HHD * CQP * 2);
  float* bqd = (float*)alloc(CQP * 4);
  u16* wkvd  = (u16*)alloc((size_t)CKV_ * D_ * 2);
  u16* wku   = (u16*)alloc((size_t)HHD * CKV_ * 2);
  u16* wvu   = (u16*)alloc((size_t)HHD * CKV_ * 2);
  u16* wob   = (u16*)alloc((size_t)D_ * HHD * 2);
  u16* cq    = (u16*)alloc((size_t)S_ * CQP * 2);
  u16* ckv   = (u16*)alloc((size_t)S_ * CKV_ * 2);
  u16* qb    = (u16*)alloc((size_t)S_ * HHD * 2);
  u16* kb    = (u16*)alloc((size_t)S_ * HHD * 2);
  u16* vT    = (u16*)alloc((size_t)HHD * S_ * 2);   // [h*128+d][s]
  u16* attnb = (u16*)alloc((size_t)S_ * HHD * 2);

  // ---- casts / padding ----
  cast_f32_bf16<<<(S_ * D_ / 4 + 255) / 256, 256, 0, stream>>>(x, xb, S_ * D_ / 4);
  pad_cast2d<<<(CQP * D_ + 255) / 256, 256, 0, stream>>>(wq_down, wqd, 96, D_, D_, CQP * D_);
  pad_cast2d<<<(HHD * CQP + 255) / 256, 256, 0, stream>>>(wq_up, wqu, HHD, 96, CQP, HHD * CQP);
  pad_bias<<<1, 128, 0, stream>>>(bq_down, bqd, 96, CQP);
  cast_f32_bf16<<<(CKV_ * D_ / 4 + 255) / 256, 256, 0, stream>>>(wkv_down, wkvd, CKV_ * D_ / 4);
  cast_f32_bf16<<<(HHD * CKV_ / 4 + 255) / 256, 256, 0, stream>>>(wk_up, wku, HHD * CKV_ / 4);
  cast_f32_bf16<<<(HHD * CKV_ / 4 + 255) / 256, 256, 0, stream>>>(wv_up, wvu, HHD * CKV_ / 4);
  cast_f32_bf16<<<(D_ * HHD / 4 + 255) / 256, 256, 0, stream>>>(wo, wob, D_ * HHD / 4);

  // ---- projections ----
  gemm_bt<u16, 1, 0><<<dim3(1, 16, 1), 256, 0, stream>>>(
      xb, wqd, cq, bqd, nullptr, D_, D_, D_, CQP, 0, 0, 0);
  gemm_bt<u16, 1, 0><<<dim3(CKV_ / 128, 16, 1), 256, 0, stream>>>(
      xb, wkvd, ckv, bkv_down, nullptr, D_, D_, D_, CKV_, 0, 0, 0);
  gemm_bt<u16, 1, 0><<<dim3(16, 16, 1), 256, 0, stream>>>(
      cq, wqu, qb, bq_up, nullptr, CQP, CQP, CQP, HHD, 0, 0, 0);
  gemm_bt<u16, 1, 0><<<dim3(16, 16, 1), 256, 0, stream>>>(
      ckv, wku, kb, bk_up, nullptr, CKV_, CKV_, CKV_, HHD, 0, 0, 0);
  // vT (HHD x S) = wv_up @ c_kv^T (+ bv_up per ROW) == v transposed
  gemm_bt<u16, 0, 1><<<dim3(16, 16, 1), 256, 0, stream>>>(
      wvu, ckv, vT, nullptr, bv_up, CKV_, CKV_, CKV_, S_, 0, 0, 0);

  // ---- RoPE (q also scaled by 1/sqrt(HD)) ----
  rope_inplace<<<(S_ * H_ * 64) / 256, 256, 0, stream>>>(qb, rc, rs, 0.08838834764831845f);
  rope_inplace<<<(S_ * H_ * 64) / 256, 256, 0, stream>>>(kb, rc, rs, 1.0f);

  // ---- fused flash attention ----
  flash_attn<<<dim3(H_, S_ / 128, 1), 256, 0, stream>>>(qb, kb, vT, attnb);

  // ---- output projection (fp32 out) ----
  gemm_bt<float, 1, 0><<<dim3(16, 16, 1), 256, 0, stream>>>(
      attnb, wob, out, bo, nullptr, HHD, HHD, HHD, D_, 0, 0, 0);
}

// Round 3
// 316.103 us; speedup vs baseline: 1.5707x; 1.3723x over previous
//
#include <hip/hip_runtime.h>
#include <cstdint>
#include <cstddef>

typedef unsigned short u16;
typedef float f32x4 __attribute__((ext_vector_type(4)));
typedef short s16x8 __attribute__((ext_vector_type(8)));

#define DI __device__ __forceinline__

static constexpr int S_  = 2048;
static constexpr int D_  = 2048;
static constexpr int H_  = 16;
static constexpr int HD_ = 128;
static constexpr int HHD = 2048;   // H*HD
static constexpr int CQP = 128;    // CQ=96 padded to 128
static constexpr int NCAT = 640;   // CQP + CKV
static constexpr int CKV_ = 512;

DI u16 f2bf(float f) {
  unsigned u = __float_as_uint(f);
  u += 0x7fffu + ((u >> 16) & 1u);   // round-to-nearest-even
  return (u16)(u >> 16);
}
DI float bf2f(u16 h) { return __uint_as_float(((unsigned)h) << 16); }

DI void store_c(float* C, long long i, float v) { C[i] = v; }
DI void store_c(u16* C, long long i, float v) { C[i] = f2bf(v); }

// DPP cross-lane (row of 16) — VALU only, no LDS port
template <int CTRL>
DI float dppf(float x) {
  return __uint_as_float((unsigned)__builtin_amdgcn_mov_dpp(
      (int)__float_as_uint(x), CTRL, 0xf, 0xf, true));
}
DI float red_max16(float x) {
  x = fmaxf(x, dppf<0xB1>(x));    // quad_perm [1,0,3,2]  (^1)
  x = fmaxf(x, dppf<0x4E>(x));    // quad_perm [2,3,0,1]  (^2)
  x = fmaxf(x, dppf<0x141>(x));   // row_half_mirror
  x = fmaxf(x, dppf<0x140>(x));   // row_mirror
  return x;
}
DI float red_sum16(float x) {
  x += dppf<0xB1>(x);
  x += dppf<0x4E>(x);
  x += dppf<0x141>(x);
  x += dppf<0x140>(x);
  return x;
}

// async 16B/lane global->LDS; LDS dest is wave-uniform base + lane*16
#define GLD16(g, l)                                                        \
  __builtin_amdgcn_global_load_lds(                                        \
      (__attribute__((address_space(1))) void*)(void*)(const void*)(g),    \
      (__attribute__((address_space(3))) void*)(l), 16, 0, 0)

// ---------------------------------------------------------------------------
// C[m][n] = sum_k A[m][k] * B[n][k]  (+bias_col[n]) (+bias_row[m])
// Tile 128 x BN (BN=128 or 64), BK=32, 256 threads. blockIdx.z strides allow
// batching or split-K (sA=sB=k-offset, sC=partial-buffer stride).
// ---------------------------------------------------------------------------
template <typename OutT, int BCOL, int BROW, int BN>
__global__ __launch_bounds__(256) void gemm_bt(
    const u16* __restrict__ A, const u16* __restrict__ B, OutT* __restrict__ C,
    const float* __restrict__ bias_col, const float* __restrict__ bias_row,
    int K, int lda, int ldb, int ldc,
    long long sA, long long sB, long long sC) {
  constexpr int MI = (BN == 128) ? 4 : 2;
  constexpr int NI = 4;
  constexpr int NCH = 8 + BN / 16;   // staging chunks (16 rows x 32 cols each)
  __shared__ __align__(16) u16 As[128 * 32];
  __shared__ __align__(16) u16 Bs[BN * 32];
  const int tid  = threadIdx.x;
  const int w    = tid >> 6;
  const int lane = tid & 63;
  const int lr   = lane & 15;
  const int lq   = lane >> 4;
  const long long m0 = (long long)blockIdx.y * 128;
  const long long n0 = (long long)blockIdx.x * BN;
  A += (long long)blockIdx.z * sA;
  B += (long long)blockIdx.z * sB;
  C += (long long)blockIdx.z * sC;
  const int wr = (BN == 128) ? (w >> 1) * 64 : w * 32;
  const int wc = (BN == 128) ? (w & 1) * 64 : 0;

  f32x4 acc[MI][NI];
#pragma unroll
  for (int i = 0; i < MI; ++i)
#pragma unroll
    for (int j = 0; j < NI; ++j)
#pragma unroll
      for (int r = 0; r < 4; ++r) acc[i][j][r] = 0.f;

  const int rch = lane >> 2, cch = (lane & 3) * 8;
  const u16* gsrc[NCH / 4];
  u16* ldst[NCH / 4];
#pragma unroll
  for (int ci = 0; ci < NCH / 4; ++ci) {
    const int c = w + ci * 4;
    if (c < 8) {
      gsrc[ci] = A + (m0 + c * 16 + rch) * lda + cch;
      ldst[ci] = &As[c * 512];
    } else {
      gsrc[ci] = B + (n0 + (c - 8) * 16 + rch) * ldb + cch;
      ldst[ci] = &Bs[(c - 8) * 512];
    }
  }

  for (int kt = 0; kt < K; kt += 32) {
    __syncthreads();
#pragma unroll
    for (int ci = 0; ci < NCH / 4; ++ci) GLD16(gsrc[ci] + kt, ldst[ci]);
    __syncthreads();

    s16x8 af[MI], bfr[NI];
#pragma unroll
    for (int tm = 0; tm < MI; ++tm)
      af[tm] = *(const s16x8*)&As[(wr + tm * 16 + lr) * 32 + lq * 8];
#pragma unroll
    for (int tn = 0; tn < NI; ++tn)
      bfr[tn] = *(const s16x8*)&Bs[(wc + tn * 16 + lr) * 32 + lq * 8];
#pragma unroll
    for (int tm = 0; tm < MI; ++tm)
#pragma unroll
      for (int tn = 0; tn < NI; ++tn)
        acc[tm][tn] = __builtin_amdgcn_mfma_f32_16x16x32_bf16(af[tm], bfr[tn],
                                                              acc[tm][tn], 0, 0, 0);
  }

#pragma unroll
  for (int tm = 0; tm < MI; ++tm)
#pragma unroll
    for (int tn = 0; tn < NI; ++tn) {
      const long long col = n0 + wc + tn * 16 + lr;
      float bc = BCOL ? bias_col[col] : 0.f;
#pragma unroll
      for (int r = 0; r < 4; ++r) {
        const long long row = m0 + wr + tm * 16 + lq * 4 + r;
        float v = acc[tm][tn][r] + bc;
        if (BROW) v += bias_row[row];
        store_c(C, row * (long long)ldc + col, v);
      }
    }
}

// ---------------------------------------------------------------------------
// combine split-K partials: dst = cast(sum_z part[z] + bias_col), float4 per thread
// ---------------------------------------------------------------------------
DI void store4(float* d, long long e, float4 s) { *(float4*)(d + e) = s; }
DI void store4(u16* d, long long e, float4 s) {
  unsigned lo = (unsigned)f2bf(s.x) | ((unsigned)f2bf(s.y) << 16);
  unsigned hi = (unsigned)f2bf(s.z) | ((unsigned)f2bf(s.w) << 16);
  *(uint2*)(d + e) = make_uint2(lo, hi);
}
template <typename OutT>
__global__ __launch_bounds__(256) void combine_z(
    const float* __restrict__ p, long long zs, int nz,
    const float* __restrict__ bias, OutT* __restrict__ dst, int ldc, int n4) {
  int i = blockIdx.x * 256 + threadIdx.x;
  if (i >= n4) return;
  long long e = (long long)i * 4;
  float4 s = *(const float4*)(p + e);
  for (int z = 1; z < nz; ++z) {
    float4 t = *(const float4*)(p + (long long)z * zs + e);
    s.x += t.x; s.y += t.y; s.z += t.z; s.w += t.w;
  }
  int c = (int)(e % ldc);
  s.x += bias[c]; s.y += bias[c + 1]; s.z += bias[c + 2]; s.w += bias[c + 3];
  store4(dst, e, s);
}

// ---------------------------------------------------------------------------
// Fused flash attention: block = (head, 128-q tile), 4 waves x 32 q-rows.
// Ks/Vs XOR-swizzled (chunk ^= row&7) -> conflict-free b128 fragment reads.
// ---------------------------------------------------------------------------
__global__ __launch_bounds__(256, 1) void flash_attn(
    const u16* __restrict__ Q, const u16* __restrict__ Kg,
    const u16* __restrict__ Vt, u16* __restrict__ Og) {
  __shared__ __align__(16) u16 Ks[128 * 128];   // [key][d], swizzled
  __shared__ __align__(16) u16 Vs[128 * 128];   // [d][key], swizzled
  __shared__ __align__(16) u16 Ps[128 * 136];   // [q][key], +8 pad
  const int h = blockIdx.x;
  const int t = blockIdx.y;
  const int tid = threadIdx.x;
  const int w = tid >> 6, lane = tid & 63, lr = lane & 15, lq = lane >> 4;
  const int qg = t * 128 + w * 32;
  const int tr = tid >> 4;
  const int cs = (tid & 15) ^ (tr & 7);   // swizzled source chunk for staging

  s16x8 qf[2][4];
#pragma unroll
  for (int mi = 0; mi < 2; ++mi)
#pragma unroll
    for (int kst = 0; kst < 4; ++kst)
      qf[mi][kst] = *(const s16x8*)&Q[(size_t)(qg + mi * 16 + lr) * HHD +
                                      h * HD_ + kst * 32 + lq * 8];

  f32x4 oacc[2][8];
  float m[2][4], l[2][4];
#pragma unroll
  for (int mi = 0; mi < 2; ++mi) {
#pragma unroll
    for (int r = 0; r < 4; ++r) { m[mi][r] = -3.0e38f; l[mi][r] = 0.f; }
#pragma unroll
    for (int f = 0; f < 8; ++f)
#pragma unroll
      for (int r = 0; r < 4; ++r) oacc[mi][f][r] = 0.f;
  }

  auto stage_k = [&](int j) {
    const u16* s0 = Kg + (size_t)(j * 128 + tr) * HHD + h * HD_ + cs * 8;
#pragma unroll
    for (int i = 0; i < 8; ++i)
      GLD16(s0 + (size_t)i * 16 * HHD, &Ks[i * 2048 + w * 512]);
  };
  auto stage_v = [&](int j) {
    const u16* s0 = Vt + (size_t)(h * 128 + tr) * S_ + j * 128 + cs * 8;
#pragma unroll
    for (int i = 0; i < 8; ++i)
      GLD16(s0 + (size_t)i * 16 * S_, &Vs[i * 2048 + w * 512]);
  };

  stage_k(0);
  stage_v(0);
  __syncthreads();

  for (int j = 0; j < 16; ++j) {
    // ---- S = Q K^T (B-frag from swizzled Ks) ----
    f32x4 sacc[2][8];
#pragma unroll
    for (int mi = 0; mi < 2; ++mi)
#pragma unroll
      for (int f = 0; f < 8; ++f)
#pragma unroll
        for (int r = 0; r < 4; ++r) sacc[mi][f][r] = 0.f;
#pragma unroll
    for (int kst = 0; kst < 4; ++kst)
#pragma unroll
      for (int f = 0; f < 8; ++f) {
        s16x8 kf = *(const s16x8*)
            &Ks[(f * 16 + lr) * 128 + (((kst * 4 + lq) ^ (lr & 7)) << 3)];
        sacc[0][f] = __builtin_amdgcn_mfma_f32_16x16x32_bf16(qf[0][kst], kf,
                                                             sacc[0][f], 0, 0, 0);
        sacc[1][f] = __builtin_amdgcn_mfma_f32_16x16x32_bf16(qf[1][kst], kf,
                                                             sacc[1][f], 0, 0, 0);
      }

    // ---- online softmax (DPP reductions, no LDS port) ----
#pragma unroll
    for (int mi = 0; mi < 2; ++mi)
#pragma unroll
      for (int r = 0; r < 4; ++r) {
        float mx = sacc[mi][0][r];
#pragma unroll
        for (int f = 1; f < 8; ++f) mx = fmaxf(mx, sacc[mi][f][r]);
        mx = red_max16(mx);
        float mn = fmaxf(m[mi][r], mx);
        float al = __expf(m[mi][r] - mn);
        m[mi][r] = mn;
        float sum = 0.f;
#pragma unroll
        for (int f = 0; f < 8; ++f) {
          float p = __expf(sacc[mi][f][r] - mn);
          sacc[mi][f][r] = p;
          sum += p;
        }
        sum = red_sum16(sum);
        l[mi][r] = l[mi][r] * al + sum;
#pragma unroll
        for (int f = 0; f < 8; ++f) oacc[mi][f][r] *= al;
      }

    // ---- P -> LDS (bf16, [q][key], stride 136) ----
#pragma unroll
    for (int mi = 0; mi < 2; ++mi)
#pragma unroll
      for (int f = 0; f < 8; ++f)
#pragma unroll
        for (int r = 0; r < 4; ++r)
          Ps[(w * 32 + mi * 16 + lq * 4 + r) * 136 + f * 16 + lr] =
              f2bf(sacc[mi][f][r]);

    __syncthreads();               // all waves done reading Ks
    if (j < 15) stage_k(j + 1);    // K prefetch hidden under PV

    // ---- O += P V (B-frag from swizzled Vs) ----
#pragma unroll
    for (int kst = 0; kst < 4; ++kst) {
      s16x8 pa0 = *(const s16x8*)&Ps[(w * 32 + lr) * 136 + kst * 32 + lq * 8];
      s16x8 pa1 = *(const s16x8*)&Ps[(w * 32 + 16 + lr) * 136 + kst * 32 + lq * 8];
#pragma unroll
      for (int f = 0; f < 8; ++f) {
        s16x8 vf = *(const s16x8*)
            &Vs[(f * 16 + lr) * 128 + (((kst * 4 + lq) ^ (lr & 7)) << 3)];
        oacc[0][f] = __builtin_amdgcn_mfma_f32_16x16x32_bf16(pa0, vf,
                                                             oacc[0][f], 0, 0, 0);
        oacc[1][f] = __builtin_amdgcn_mfma_f32_16x16x32_bf16(pa1, vf,
                                                             oacc[1][f], 0, 0, 0);
      }
    }
    __syncthreads();               // all waves done reading Vs
    if (j < 15) stage_v(j + 1);    // V prefetch hidden under next S-phase
  }

  // ---- epilogue: O / l ----
#pragma unroll
  for (int mi = 0; mi < 2; ++mi) {
    float inv[4];
#pragma unroll
    for (int r = 0; r < 4; ++r) inv[r] = 1.f / l[mi][r];
#pragma unroll
    for (int f = 0; f < 8; ++f)
#pragma unroll
      for (int r = 0; r < 4; ++r)
        Og[(size_t)(qg + mi * 16 + lq * 4 + r) * HHD + h * HD_ + f * 16 + lr] =
            f2bf(oacc[mi][f][r] * inv[r]);
  }
}

// ---------------------------------------------------------------------------
__global__ __launch_bounds__(256) void cast_f32_bf16(const float* __restrict__ s,
                                                     u16* __restrict__ d, int n4) {
  int i = blockIdx.x * 256 + threadIdx.x;
  if (i >= n4) return;
  float4 f = ((const float4*)s)[i];
  unsigned lo = (unsigned)f2bf(f.x) | ((unsigned)f2bf(f.y) << 16);
  unsigned hi = (unsigned)f2bf(f.z) | ((unsigned)f2bf(f.w) << 16);
  ((uint2*)d)[i] = make_uint2(lo, hi);
}

__global__ __launch_bounds__(256) void pad_cast2d(const float* __restrict__ s,
                                                  u16* __restrict__ d, int rs, int cs,
                                                  int cd, int nd) {
  int i = blockIdx.x * 256 + threadIdx.x;
  if (i >= nd) return;
  int r = i / cd, c = i % cd;
  float v = (r < rs && c < cs) ? s[r * cs + c] : 0.f;
  d[i] = f2bf(v);
}

// wcat[n][k]: n<96 -> wq_down, 96..128 -> 0, >=128 -> wkv_down[n-128]
__global__ __launch_bounds__(256) void build_wcat(const float* __restrict__ wqd,
                                                  const float* __restrict__ wkvd,
                                                  u16* __restrict__ d) {
  int i = blockIdx.x * 256 + threadIdx.x;   // NCAT*D_ total
  int n = i >> 11, k = i & 2047;
  float v = (n < 96) ? wqd[n * D_ + k] : (n < 128 ? 0.f : wkvd[(n - 128) * D_ + k]);
  d[i] = f2bf(v);
}
__global__ void build_bcat(const float* __restrict__ bqd,
                           const float* __restrict__ bkvd, float* __restrict__ d) {
  int i = threadIdx.x;   // 640
  d[i] = (i < 96) ? bqd[i] : (i < 128 ? 0.f : bkvd[i - 128]);
}

__global__ __launch_bounds__(256) void rope_inplace(u16* __restrict__ X,
                                                    const float* __restrict__ cs,
                                                    const float* __restrict__ sn,
                                                    float scale) {
  int id = blockIdx.x * 256 + threadIdx.x;  // S*H*64 total
  int d = id & 63;
  int h = (id >> 6) & 15;
  int s = id >> 10;
  long long b = (long long)s * HHD + h * HD_ + d;
  float x1 = bf2f(X[b]), x2 = bf2f(X[b + 64]);
  int cb = s * HD_ + d;
  float o1 = (x1 * cs[cb] - x2 * sn[cb]) * scale;
  float o2 = (x2 * cs[cb + 64] + x1 * sn[cb + 64]) * scale;
  X[b] = f2bf(o1);
  X[b + 64] = f2bf(o2);
}

// ---------------------------------------------------------------------------
extern "C" void kernel_launch(void* const* d_in, const int* in_sizes, int n_in,
                              void* d_out, int out_size, void* d_ws, size_t ws_size,
                              hipStream_t stream) {
  (void)in_sizes; (void)n_in; (void)out_size; (void)ws_size;
  const float* x        = (const float*)d_in[0];
  const float* rc       = (const float*)d_in[1];
  const float* rs       = (const float*)d_in[2];
  const float* wq_down  = (const float*)d_in[3];
  const float* bq_down  = (const float*)d_in[4];
  const float* wq_up    = (const float*)d_in[5];
  const float* bq_up    = (const float*)d_in[6];
  const float* wkv_down = (const float*)d_in[7];
  const float* bkv_down = (const float*)d_in[8];
  const float* wk_up    = (const float*)d_in[9];
  const float* bk_up    = (const float*)d_in[10];
  const float* wv_up    = (const float*)d_in[11];
  const float* bv_up    = (const float*)d_in[12];
  const float* wo       = (const float*)d_in[13];
  const float* bo       = (const float*)d_in[14];
  float* out = (float*)d_out;

  char* ws = (char*)d_ws;
  size_t off = 0;
  auto alloc = [&](size_t bytes) -> void* {
    off = (off + 255) & ~(size_t)255;
    void* p = ws + off;
    off += bytes;
    return p;
  };

  u16* xb      = (u16*)alloc((size_t)S_ * D_ * 2);
  u16* wcat    = (u16*)alloc((size_t)NCAT * D_ * 2);
  float* bcat  = (float*)alloc(NCAT * 4);
  u16* wqu     = (u16*)alloc((size_t)HHD * CQP * 2);
  u16* wku     = (u16*)alloc((size_t)HHD * CKV_ * 2);
  u16* wvu     = (u16*)alloc((size_t)HHD * CKV_ * 2);
  u16* wob     = (u16*)alloc((size_t)D_ * HHD * 2);
  u16* ccat    = (u16*)alloc((size_t)S_ * NCAT * 2);
  float* pcat  = (float*)alloc((size_t)4 * S_ * NCAT * 4);
  u16* qb      = (u16*)alloc((size_t)S_ * HHD * 2);
  u16* kb      = (u16*)alloc((size_t)S_ * HHD * 2);
  u16* vT      = (u16*)alloc((size_t)HHD * S_ * 2);   // [h*128+d][s]
  u16* attnb   = (u16*)alloc((size_t)S_ * HHD * 2);
  float* pout  = (float*)alloc((size_t)2 * S_ * D_ * 4);

  // ---- casts / packing ----
  cast_f32_bf16<<<(S_ * D_ / 4 + 255) / 256, 256, 0, stream>>>(x, xb, S_ * D_ / 4);
  build_wcat<<<(NCAT * D_) / 256, 256, 0, stream>>>(wq_down, wkv_down, wcat);
  build_bcat<<<1, NCAT, 0, stream>>>(bq_down, bkv_down, bcat);
  pad_cast2d<<<(HHD * CQP + 255) / 256, 256, 0, stream>>>(wq_up, wqu, HHD, 96, CQP, HHD * CQP);
  cast_f32_bf16<<<(HHD * CKV_ / 4 + 255) / 256, 256, 0, stream>>>(wk_up, wku, HHD * CKV_ / 4);
  cast_f32_bf16<<<(HHD * CKV_ / 4 + 255) / 256, 256, 0, stream>>>(wv_up, wvu, HHD * CKV_ / 4);
  cast_f32_bf16<<<(D_ * HHD / 4 + 255) / 256, 256, 0, stream>>>(wo, wob, D_ * HHD / 4);

  // ---- fused c_q|c_kv projection, split-K x4 ----
  gemm_bt<float, 0, 0, 64><<<dim3(NCAT / 64, 16, 4), 256, 0, stream>>>(
      xb, wcat, pcat, nullptr, nullptr, 512, D_, D_, NCAT,
      512, 512, (long long)S_ * NCAT);
  combine_z<u16><<<(S_ * NCAT / 4 + 255) / 256, 256, 0, stream>>>(
      pcat, (long long)S_ * NCAT, 4, bcat, ccat, NCAT, S_ * NCAT / 4);

  // ---- up-projections (A = slices of ccat, lda = NCAT) ----
  gemm_bt<u16, 1, 0, 128><<<dim3(16, 16, 1), 256, 0, stream>>>(
      ccat, wqu, qb, bq_up, nullptr, CQP, NCAT, CQP, HHD, 0, 0, 0);
  gemm_bt<u16, 1, 0, 128><<<dim3(16, 16, 1), 256, 0, stream>>>(
      ccat + CQP, wku, kb, bk_up, nullptr, CKV_, NCAT, CKV_, HHD, 0, 0, 0);
  // vT (HHD x S) = wv_up @ c_kv^T (+ bv_up per ROW)
  gemm_bt<u16, 0, 1, 128><<<dim3(16, 16, 1), 256, 0, stream>>>(
      wvu, ccat + CQP, vT, nullptr, bv_up, CKV_, CKV_, NCAT, S_, 0, 0, 0);

  // ---- RoPE (q also scaled by 1/sqrt(HD)) ----
  rope_inplace<<<(S_ * H_ * 64) / 256, 256, 0, stream>>>(qb, rc, rs, 0.08838834764831845f);
  rope_inplace<<<(S_ * H_ * 64) / 256, 256, 0, stream>>>(kb, rc, rs, 1.0f);

  // ---- fused flash attention ----
  flash_attn<<<dim3(H_, S_ / 128, 1), 256, 0, stream>>>(qb, kb, vT, attnb);

  // ---- output projection, split-K x2, f32 combine w/ bias ----
  gemm_bt<float, 0, 0, 128><<<dim3(16, 16, 2), 256, 0, stream>>>(
      attnb, wob, pout, nullptr, nullptr, 1024, HHD, HHD, D_,
      1024, 1024, (long long)S_ * D_);
  combine_z<float><<<(S_ * D_ / 4 + 255) / 256, 256, 0, stream>>>(
      pout, (long long)S_ * D_, 2, bo, out, D_, S_ * D_ / 4);
}

// Round 4
// 286.709 us; speedup vs baseline: 1.7317x; 1.1025x over previous
//
#include <hip/hip_runtime.h>
#include <cstdint>
#include <cstddef>

typedef unsigned short u16;
typedef float f32x4 __attribute__((ext_vector_type(4)));
typedef short s16x8 __attribute__((ext_vector_type(8)));

#define DI __device__ __forceinline__

static constexpr int S_  = 2048;
static constexpr int D_  = 2048;
static constexpr int H_  = 16;
static constexpr int HD_ = 128;
static constexpr int HHD = 2048;   // H*HD
static constexpr int CQP = 128;    // CQ=96 padded to 128
static constexpr int NCAT = 640;   // CQP + CKV
static constexpr int CKV_ = 512;

DI u16 f2bf(float f) {
  unsigned u = __float_as_uint(f);
  u += 0x7fffu + ((u >> 16) & 1u);   // round-to-nearest-even
  return (u16)(u >> 16);
}
DI float bf2f(u16 h) { return __uint_as_float(((unsigned)h) << 16); }

DI void store_c(float* C, long long i, float v) { C[i] = v; }
DI void store_c(u16* C, long long i, float v) { C[i] = f2bf(v); }

// DPP cross-lane (row of 16) — VALU only, no LDS port
template <int CTRL>
DI float dppf(float x) {
  return __uint_as_float((unsigned)__builtin_amdgcn_mov_dpp(
      (int)__float_as_uint(x), CTRL, 0xf, 0xf, true));
}
DI float red_max16(float x) {
  x = fmaxf(x, dppf<0xB1>(x));
  x = fmaxf(x, dppf<0x4E>(x));
  x = fmaxf(x, dppf<0x141>(x));
  x = fmaxf(x, dppf<0x140>(x));
  return x;
}
DI float red_sum16(float x) {
  x += dppf<0xB1>(x);
  x += dppf<0x4E>(x);
  x += dppf<0x141>(x);
  x += dppf<0x140>(x);
  return x;
}

// async 16B/lane global->LDS; LDS dest is wave-uniform base + lane*16
#define GLD16(g, l)                                                        \
  __builtin_amdgcn_global_load_lds(                                        \
      (__attribute__((address_space(1))) void*)(void*)(const void*)(g),    \
      (__attribute__((address_space(3))) void*)(l), 16, 0, 0)

// ---------------------------------------------------------------------------
// C[m][n] = sum_k A[m][k] * B[n][k]  (+bias_col[n]) (+bias_row[m])
// Double-buffered LDS: stage(kt+32) issued before compute(kt) -> per-iter
// time ~ max(load latency, compute) instead of sum (latency-bound regime).
// ---------------------------------------------------------------------------
template <typename OutT, int BCOL, int BROW, int BN>
__global__ __launch_bounds__(256) void gemm_bt(
    const u16* __restrict__ A, const u16* __restrict__ B, OutT* __restrict__ C,
    const float* __restrict__ bias_col, const float* __restrict__ bias_row,
    int K, int lda, int ldb, int ldc,
    long long sA, long long sB, long long sC) {
  constexpr int MI = (BN == 128) ? 4 : 2;
  constexpr int NI = 4;
  constexpr int NCH = 8 + BN / 16;   // staging chunks (16 rows x 32 cols each)
  constexpr int NC4 = NCH / 4;
  __shared__ __align__(16) u16 As[2 * 128 * 32];
  __shared__ __align__(16) u16 Bs[2 * BN * 32];
  const int tid  = threadIdx.x;
  const int w    = tid >> 6;
  const int lane = tid & 63;
  const int lr   = lane & 15;
  const int lq   = lane >> 4;
  const long long m0 = (long long)blockIdx.y * 128;
  const long long n0 = (long long)blockIdx.x * BN;
  A += (long long)blockIdx.z * sA;
  B += (long long)blockIdx.z * sB;
  C += (long long)blockIdx.z * sC;
  const int wr = (BN == 128) ? (w >> 1) * 64 : w * 32;
  const int wc = (BN == 128) ? (w & 1) * 64 : 0;

  f32x4 acc[MI][NI];
#pragma unroll
  for (int i = 0; i < MI; ++i)
#pragma unroll
    for (int j = 0; j < NI; ++j)
#pragma unroll
      for (int r = 0; r < 4; ++r) acc[i][j][r] = 0.f;

  const int rch = lane >> 2, cch = (lane & 3) * 8;
  const u16* gsrc[NC4];
  u16* ldst[NC4];
  int bstep[NC4];
#pragma unroll
  for (int ci = 0; ci < NC4; ++ci) {
    const int c = w + ci * 4;
    if (c < 8) {
      gsrc[ci] = A + (m0 + c * 16 + rch) * lda + cch;
      ldst[ci] = &As[c * 512];
      bstep[ci] = 128 * 32;
    } else {
      gsrc[ci] = B + (n0 + (c - 8) * 16 + rch) * ldb + cch;
      ldst[ci] = &Bs[(c - 8) * 512];
      bstep[ci] = BN * 32;
    }
  }
  auto stage = [&](int kt, int b) {
#pragma unroll
    for (int ci = 0; ci < NC4; ++ci) GLD16(gsrc[ci] + kt, ldst[ci] + b * bstep[ci]);
  };

  stage(0, 0);
  int cur = 0;
  for (int kt = 0; kt < K; kt += 32) {
    __syncthreads();                       // drains stage(kt) into buf cur
    if (kt + 32 < K) stage(kt + 32, cur ^ 1);   // overlaps compute below
    const u16* Ab = &As[cur * 128 * 32];
    const u16* Bb = &Bs[cur * BN * 32];

    s16x8 af[MI], bfr[NI];
#pragma unroll
    for (int tm = 0; tm < MI; ++tm)
      af[tm] = *(const s16x8*)&Ab[(wr + tm * 16 + lr) * 32 + lq * 8];
#pragma unroll
    for (int tn = 0; tn < NI; ++tn)
      bfr[tn] = *(const s16x8*)&Bb[(wc + tn * 16 + lr) * 32 + lq * 8];
#pragma unroll
    for (int tm = 0; tm < MI; ++tm)
#pragma unroll
      for (int tn = 0; tn < NI; ++tn)
        acc[tm][tn] = __builtin_amdgcn_mfma_f32_16x16x32_bf16(af[tm], bfr[tn],
                                                              acc[tm][tn], 0, 0, 0);
    cur ^= 1;
  }

#pragma unroll
  for (int tm = 0; tm < MI; ++tm)
#pragma unroll
    for (int tn = 0; tn < NI; ++tn) {
      const long long col = n0 + wc + tn * 16 + lr;
      float bc = BCOL ? bias_col[col] : 0.f;
#pragma unroll
      for (int r = 0; r < 4; ++r) {
        const long long row = m0 + wr + tm * 16 + lq * 4 + r;
        float v = acc[tm][tn][r] + bc;
        if (BROW) v += bias_row[row];
        store_c(C, row * (long long)ldc + col, v);
      }
    }
}

// ---------------------------------------------------------------------------
DI void store4(float* d, long long e, float4 s) { *(float4*)(d + e) = s; }
DI void store4(u16* d, long long e, float4 s) {
  unsigned lo = (unsigned)f2bf(s.x) | ((unsigned)f2bf(s.y) << 16);
  unsigned hi = (unsigned)f2bf(s.z) | ((unsigned)f2bf(s.w) << 16);
  *(uint2*)(d + e) = make_uint2(lo, hi);
}
template <typename OutT>
__global__ __launch_bounds__(256) void combine_z(
    const float* __restrict__ p, long long zs, int nz,
    const float* __restrict__ bias, OutT* __restrict__ dst, int ldc, int n4) {
  int i = blockIdx.x * 256 + threadIdx.x;
  if (i >= n4) return;
  long long e = (long long)i * 4;
  float4 s = *(const float4*)(p + e);
  for (int z = 1; z < nz; ++z) {
    float4 t = *(const float4*)(p + (long long)z * zs + e);
    s.x += t.x; s.y += t.y; s.z += t.z; s.w += t.w;
  }
  int c = (int)(e % ldc);
  s.x += bias[c]; s.y += bias[c + 1]; s.z += bias[c + 2]; s.w += bias[c + 3];
  store4(dst, e, s);
}

// ---------------------------------------------------------------------------
// Fused flash attention: block = (head, 128-q tile), 8 waves x 16 q-rows
// (512 threads -> 2 waves/SIMD). Ks/Vs XOR-swizzled; Ps stride 132.
// ---------------------------------------------------------------------------
__global__ __launch_bounds__(512, 2) void flash_attn(
    const u16* __restrict__ Q, const u16* __restrict__ Kg,
    const u16* __restrict__ Vt, u16* __restrict__ Og) {
  __shared__ __align__(16) u16 Ks[128 * 128];   // [key][d], swizzled
  __shared__ __align__(16) u16 Vs[128 * 128];   // [d][key], swizzled
  __shared__ __align__(16) u16 Ps[128 * 132];   // [q][key]
  const int h = blockIdx.x;
  const int t = blockIdx.y;
  const int tid = threadIdx.x;
  const int w = tid >> 6, lane = tid & 63, lr = lane & 15, lq = lane >> 4;
  const int qg = t * 128 + w * 16;
  const int rsub = w * 4 + (lane >> 4);        // row within 32-row group
  const int csw  = (lane & 15) ^ (rsub & 7);   // swizzled source chunk

  s16x8 qf[4];
#pragma unroll
  for (int kst = 0; kst < 4; ++kst)
    qf[kst] = *(const s16x8*)&Q[(size_t)(qg + lr) * HHD + h * HD_ + kst * 32 + lq * 8];

  f32x4 oacc[8];
  float m[4], l[4];
#pragma unroll
  for (int r = 0; r < 4; ++r) { m[r] = -3.0e38f; l[r] = 0.f; }
#pragma unroll
  for (int f = 0; f < 8; ++f)
#pragma unroll
    for (int r = 0; r < 4; ++r) oacc[f][r] = 0.f;

  auto stage_k = [&](int j) {
#pragma unroll
    for (int i = 0; i < 4; ++i) {
      const u16* s0 = Kg + (size_t)(j * 128 + i * 32 + rsub) * HHD + h * HD_ + csw * 8;
      GLD16(s0, &Ks[(i * 32 + w * 4) * 128]);
    }
  };
  auto stage_v = [&](int j) {
#pragma unroll
    for (int i = 0; i < 4; ++i) {
      const u16* s0 = Vt + (size_t)(h * HD_ + i * 32 + rsub) * S_ + j * 128 + csw * 8;
      GLD16(s0, &Vs[(i * 32 + w * 4) * 128]);
    }
  };

  stage_k(0);
  stage_v(0);
  __syncthreads();

  for (int j = 0; j < 16; ++j) {
    // ---- S = Q K^T ----
    f32x4 sacc[8];
#pragma unroll
    for (int f = 0; f < 8; ++f)
#pragma unroll
      for (int r = 0; r < 4; ++r) sacc[f][r] = 0.f;
#pragma unroll
    for (int kst = 0; kst < 4; ++kst)
#pragma unroll
      for (int f = 0; f < 8; ++f) {
        s16x8 kf = *(const s16x8*)
            &Ks[(f * 16 + lr) * 128 + (((kst * 4 + lq) ^ (lr & 7)) << 3)];
        sacc[f] = __builtin_amdgcn_mfma_f32_16x16x32_bf16(qf[kst], kf, sacc[f], 0, 0, 0);
      }

    // ---- online softmax (DPP row-16 reductions) ----
#pragma unroll
    for (int r = 0; r < 4; ++r) {
      float mx = sacc[0][r];
#pragma unroll
      for (int f = 1; f < 8; ++f) mx = fmaxf(mx, sacc[f][r]);
      mx = red_max16(mx);
      float mn = fmaxf(m[r], mx);
      float al = __expf(m[r] - mn);
      m[r] = mn;
      float sum = 0.f;
#pragma unroll
      for (int f = 0; f < 8; ++f) {
        float p = __expf(sacc[f][r] - mn);
        sacc[f][r] = p;
        sum += p;
      }
      sum = red_sum16(sum);
      l[r] = l[r] * al + sum;
#pragma unroll
      for (int f = 0; f < 8; ++f) oacc[f][r] *= al;
    }

    // ---- P -> LDS ----
#pragma unroll
    for (int f = 0; f < 8; ++f)
#pragma unroll
      for (int r = 0; r < 4; ++r)
        Ps[(w * 16 + lq * 4 + r) * 132 + f * 16 + lr] = f2bf(sacc[f][r]);

    __syncthreads();               // all waves done reading Ks
    if (j < 15) stage_k(j + 1);    // overlaps PV

    // ---- O += P V ----
#pragma unroll
    for (int kst = 0; kst < 4; ++kst) {
      s16x8 pa = *(const s16x8*)&Ps[(w * 16 + lr) * 132 + kst * 32 + lq * 8];
#pragma unroll
      for (int f = 0; f < 8; ++f) {
        s16x8 vf = *(const s16x8*)
            &Vs[(f * 16 + lr) * 128 + (((kst * 4 + lq) ^ (lr & 7)) << 3)];
        oacc[f] = __builtin_amdgcn_mfma_f32_16x16x32_bf16(pa, vf, oacc[f], 0, 0, 0);
      }
    }
    __syncthreads();               // all waves done reading Vs
    if (j < 15) stage_v(j + 1);    // overlaps next S-phase
  }

  // ---- epilogue: O / l ----
  float inv[4];
#pragma unroll
  for (int r = 0; r < 4; ++r) inv[r] = 1.f / l[r];
#pragma unroll
  for (int f = 0; f < 8; ++f)
#pragma unroll
    for (int r = 0; r < 4; ++r)
      Og[(size_t)(qg + lq * 4 + r) * HHD + h * HD_ + f * 16 + lr] =
          f2bf(oacc[f][r] * inv[r]);
}

// ---------------------------------------------------------------------------
// One fused prep kernel: all f32->bf16 weight casts/padding + bcat.
// vec4 segment ladder.
// ---------------------------------------------------------------------------
DI void cast4(const float* __restrict__ s, u16* __restrict__ d, int v) {
  float4 f = ((const float4*)s)[v];
  unsigned lo = (unsigned)f2bf(f.x) | ((unsigned)f2bf(f.y) << 16);
  unsigned hi = (unsigned)f2bf(f.z) | ((unsigned)f2bf(f.w) << 16);
  ((uint2*)d)[v] = make_uint2(lo, hi);
}
DI void store_bf4(u16* __restrict__ d, int i, float4 f) {
  unsigned lo = (unsigned)f2bf(f.x) | ((unsigned)f2bf(f.y) << 16);
  unsigned hi = (unsigned)f2bf(f.z) | ((unsigned)f2bf(f.w) << 16);
  *(uint2*)(d + i) = make_uint2(lo, hi);
}
static constexpr int PV_XB   = 1048576;
static constexpr int PV_WCAT = 327680;
static constexpr int PV_WQU  = 65536;
static constexpr int PV_WKU  = 262144;
static constexpr int PV_WVU  = 262144;
static constexpr int PV_WOB  = 1048576;
static constexpr int PV_BCAT = 160;
static constexpr int PV_TOT  = PV_XB + PV_WCAT + PV_WQU + PV_WKU + PV_WVU + PV_WOB + PV_BCAT;

__global__ __launch_bounds__(256) void prep(
    const float* __restrict__ x, const float* __restrict__ wqd_s,
    const float* __restrict__ wkvd_s, const float* __restrict__ wqu_s,
    const float* __restrict__ wku_s, const float* __restrict__ wvu_s,
    const float* __restrict__ wo_s, const float* __restrict__ bqd_s,
    const float* __restrict__ bkvd_s,
    u16* __restrict__ xb, u16* __restrict__ wcat, u16* __restrict__ wqu,
    u16* __restrict__ wku, u16* __restrict__ wvu, u16* __restrict__ wob,
    float* __restrict__ bcat) {
  int v = blockIdx.x * 256 + threadIdx.x;
  if (v >= PV_TOT) return;
  if (v < PV_XB) { cast4(x, xb, v); return; }
  v -= PV_XB;
  if (v < PV_WCAT) {            // wcat[n][k]: n<96 wq_down, <128 zero, else wkv_down
    int i = v * 4, n = i >> 11, k = i & 2047;
    float4 o = make_float4(0.f, 0.f, 0.f, 0.f);
    if (n < 96)       o = *(const float4*)&wqd_s[n * D_ + k];
    else if (n >= 128) o = *(const float4*)&wkvd_s[(n - 128) * D_ + k];
    store_bf4(wcat, i, o);
    return;
  }
  v -= PV_WCAT;
  if (v < PV_WQU) {             // wqu: 2048 x 128, src 2048 x 96, zero-pad
    int i = v * 4, r = i >> 7, c = i & 127;
    float4 o = (c < 96) ? *(const float4*)&wqu_s[r * 96 + c]
                        : make_float4(0.f, 0.f, 0.f, 0.f);
    store_bf4(wqu, i, o);
    return;
  }
  v -= PV_WQU;
  if (v < PV_WKU) { cast4(wku_s, wku, v); return; }
  v -= PV_WKU;
  if (v < PV_WVU) { cast4(wvu_s, wvu, v); return; }
  v -= PV_WVU;
  if (v < PV_WOB) { cast4(wo_s, wob, v); return; }
  v -= PV_WOB;
  {                             // bcat (640 floats)
    int i = v * 4;
    float4 o;
    float* po = &o.x;
#pragma unroll
    for (int jj = 0; jj < 4; ++jj) {
      int e = i + jj;
      po[jj] = (e < 96) ? bqd_s[e] : (e < 128 ? 0.f : bkvd_s[e - 128]);
    }
    *(float4*)&bcat[i] = o;
  }
}

// fused RoPE for q (scaled) and k
__global__ __launch_bounds__(256) void rope2(u16* __restrict__ qb,
                                             u16* __restrict__ kb,
                                             const float* __restrict__ cs,
                                             const float* __restrict__ sn) {
  int id = blockIdx.x * 256 + threadIdx.x;    // 2*S*H*64
  const bool isq = id < S_ * H_ * 64;
  if (!isq) id -= S_ * H_ * 64;
  u16* X = isq ? qb : kb;
  const float scale = isq ? 0.08838834764831845f : 1.0f;
  int d = id & 63;
  int h = (id >> 6) & 15;
  int s = id >> 10;
  long long b = (long long)s * HHD + h * HD_ + d;
  float x1 = bf2f(X[b]), x2 = bf2f(X[b + 64]);
  int cb = s * HD_ + d;
  float o1 = (x1 * cs[cb] - x2 * sn[cb]) * scale;
  float o2 = (x2 * cs[cb + 64] + x1 * sn[cb + 64]) * scale;
  X[b] = f2bf(o1);
  X[b + 64] = f2bf(o2);
}

// ---------------------------------------------------------------------------
extern "C" void kernel_launch(void* const* d_in, const int* in_sizes, int n_in,
                              void* d_out, int out_size, void* d_ws, size_t ws_size,
                              hipStream_t stream) {
  (void)in_sizes; (void)n_in; (void)out_size; (void)ws_size;
  const float* x        = (const float*)d_in[0];
  const float* rc       = (const float*)d_in[1];
  const float* rs       = (const float*)d_in[2];
  const float* wq_down  = (const float*)d_in[3];
  const float* bq_down  = (const float*)d_in[4];
  const float* wq_up    = (const float*)d_in[5];
  const float* bq_up    = (const float*)d_in[6];
  const float* wkv_down = (const float*)d_in[7];
  const float* bkv_down = (const float*)d_in[8];
  const float* wk_up    = (const float*)d_in[9];
  const float* bk_up    = (const float*)d_in[10];
  const float* wv_up    = (const float*)d_in[11];
  const float* bv_up    = (const float*)d_in[12];
  const float* wo       = (const float*)d_in[13];
  const float* bo       = (const float*)d_in[14];
  float* out = (float*)d_out;

  char* ws = (char*)d_ws;
  size_t off = 0;
  auto alloc = [&](size_t bytes) -> void* {
    off = (off + 255) & ~(size_t)255;
    void* p = ws + off;
    off += bytes;
    return p;
  };

  u16* xb      = (u16*)alloc((size_t)S_ * D_ * 2);
  u16* wcat    = (u16*)alloc((size_t)NCAT * D_ * 2);
  float* bcat  = (float*)alloc(NCAT * 4);
  u16* wqu     = (u16*)alloc((size_t)HHD * CQP * 2);
  u16* wku     = (u16*)alloc((size_t)HHD * CKV_ * 2);
  u16* wvu     = (u16*)alloc((size_t)HHD * CKV_ * 2);
  u16* wob     = (u16*)alloc((size_t)D_ * HHD * 2);
  u16* ccat    = (u16*)alloc((size_t)S_ * NCAT * 2);
  float* pcat  = (float*)alloc((size_t)4 * S_ * NCAT * 4);
  u16* qb      = (u16*)alloc((size_t)S_ * HHD * 2);
  u16* kb      = (u16*)alloc((size_t)S_ * HHD * 2);
  u16* vT      = (u16*)alloc((size_t)HHD * S_ * 2);   // [h*128+d][s]
  u16* attnb   = (u16*)alloc((size_t)S_ * HHD * 2);

  // ---- fused prep ----
  prep<<<(PV_TOT + 255) / 256, 256, 0, stream>>>(
      x, wq_down, wkv_down, wq_up, wk_up, wv_up, wo, bq_down, bkv_down,
      xb, wcat, wqu, wku, wvu, wob, bcat);

  // ---- fused c_q|c_kv projection, split-K x4 ----
  gemm_bt<float, 0, 0, 64><<<dim3(NCAT / 64, 16, 4), 256, 0, stream>>>(
      xb, wcat, pcat, nullptr, nullptr, 512, D_, D_, NCAT,
      512, 512, (long long)S_ * NCAT);
  combine_z<u16><<<(S_ * NCAT / 4 + 255) / 256, 256, 0, stream>>>(
      pcat, (long long)S_ * NCAT, 4, bcat, ccat, NCAT, S_ * NCAT / 4);

  // ---- up-projections (A = slices of ccat, lda = NCAT) ----
  gemm_bt<u16, 1, 0, 128><<<dim3(16, 16, 1), 256, 0, stream>>>(
      ccat, wqu, qb, bq_up, nullptr, CQP, NCAT, CQP, HHD, 0, 0, 0);
  gemm_bt<u16, 1, 0, 128><<<dim3(16, 16, 1), 256, 0, stream>>>(
      ccat + CQP, wku, kb, bk_up, nullptr, CKV_, NCAT, CKV_, HHD, 0, 0, 0);
  // vT (HHD x S) = wv_up @ c_kv^T (+ bv_up per ROW)
  gemm_bt<u16, 0, 1, 128><<<dim3(16, 16, 1), 256, 0, stream>>>(
      wvu, ccat + CQP, vT, nullptr, bv_up, CKV_, CKV_, NCAT, S_, 0, 0, 0);

  // ---- RoPE (q scaled by 1/sqrt(HD)) ----
  rope2<<<(2 * S_ * H_ * 64) / 256, 256, 0, stream>>>(qb, kb, rc, rs);

  // ---- fused flash attention (512 threads) ----
  flash_attn<<<dim3(H_, S_ / 128, 1), 512, 0, stream>>>(qb, kb, vT, attnb);

  // ---- output projection (f32 out + bias, no split) ----
  gemm_bt<float, 1, 0, 128><<<dim3(16, 16, 1), 256, 0, stream>>>(
      attnb, wob, out, bo, nullptr, HHD, HHD, HHD, D_, 0, 0, 0);
}